// Round 22
// baseline (132.119 us; speedup 1.0000x reference)
//
#include <hip/hip_runtime.h>
#include <hip/hip_bf16.h>

typedef unsigned short u16;
typedef unsigned int u32;
typedef __attribute__((ext_vector_type(8))) short short8;   // 8 bf16 for MFMA frags
typedef __attribute__((ext_vector_type(8))) u16 ushort8;
typedef __attribute__((ext_vector_type(4))) float f32x4;

// ---------- constants ----------
#define BB 2048
#define SS 8
#define DNUM 8
#define LL 50
#define EDIM 16
#define FDIM 512
#define HID1 256
#define HID2 128
#define VF 100000
#define KDNN 1216          // 1160 padded to 64-multiple
#define ROWS (BB*LL)       // 102400

// ---------- helpers ----------
__device__ inline u16 f2bf(float x) {            // HW RNE cvt (compiler packs)
    return __builtin_bit_cast(u16, __float2bfloat16(x));
}
__device__ inline float bf2f(u16 b) {
    u32 u = ((u32)b) << 16;
    return __builtin_bit_cast(float, u);
}
__device__ inline void load16_lds(const void* g, void* l) {
    __builtin_amdgcn_global_load_lds(
        (const __attribute__((address_space(1))) u32*)g,
        (__attribute__((address_space(3))) u32*)l, 16, 0, 0);
}
__device__ inline float wave_sum(float v) {
    #pragma unroll
    for (int off = 32; off > 0; off >>= 1) v += __shfl_xor(v, off, 64);
    return v;
}
__device__ inline float wave_max(float v) {
    #pragma unroll
    for (int off = 32; off > 0; off >>= 1) v = fmaxf(v, __shfl_xor(v, off, 64));
    return v;
}
__device__ inline void cvt8(const float4& a, const float4& b, ushort8& o) {
    o[0]=f2bf(a.x); o[1]=f2bf(a.y); o[2]=f2bf(a.z); o[3]=f2bf(a.w);
    o[4]=f2bf(b.x); o[5]=f2bf(b.y); o[6]=f2bf(b.z); o[7]=f2bf(b.w);
}

// ---------- K0: weight prep + per-b gather ----------
// WHP_S [128n][1024k] PRE-SWIZZLED within each 32-k tile:
//   ks = (k&~31) | ((k&31) ^ ((n&3)<<3))
#define PREP_BLKS 2112
__global__ __launch_bounds__(256) void prep_small(
    const float* __restrict__ ft,
    const float* __restrict__ w1, const float* __restrict__ dw1,
    const float* __restrict__ dw2,
    u16* __restrict__ WHP_S, u16* __restrict__ WQ_T,
    u16* __restrict__ W1D_T, u16* __restrict__ W2D_T,
    const int* __restrict__ sparse_ids, const float* __restrict__ dense,
    const int* __restrict__ feedid, const float* __restrict__ emb_tables,
    u16* __restrict__ dnn_in, u16* __restrict__ A_q)
{
    int blk = blockIdx.x, t = threadIdx.x;
    if (blk < PREP_BLKS) {
        int idx = blk * 256 + t;
        if (idx < 131072) {
            int n = idx >> 10, k = idx & 1023;
            float v;
            if (k < 512) v = w1[(512 + k) * 128 + n] - w1[(1024 + k) * 128 + n];
            else         v = w1[(1024 + k) * 128 + n];   // 1536 + (k-512)
            int ks = (k & ~31) | ((k & 31) ^ ((n & 3) << 3));
            WHP_S[n * 1024 + ks] = f2bf(v);
        } else if (idx < 196608) {
            int i = idx - 131072;
            int n = i >> 9, k = i & 511;
            WQ_T[n * 512 + k] = f2bf(w1[k * 128 + n] + w1[(1024 + k) * 128 + n]);
        } else if (idx < 507904) {
            int i = idx - 196608;
            int n = i / KDNN, k = i - n * KDNN;
            W1D_T[i] = (k < 1160) ? f2bf(dw1[k * HID1 + n]) : (u16)0;
        } else if (idx < 540672) {
            int i = idx - 507904;
            int n = i >> 8, k = i & 255;
            W2D_T[i] = f2bf(dw2[k * HID2 + n]);
        }
    } else {
        int b = blk - PREP_BLKS;
        u16* drow = dnn_in + (size_t)b * KDNN;
        if (t < 128) {
            int s = t >> 4, e = t & 15;
            int id = sparse_ids[b * SS + s];
            float v = emb_tables[(size_t)s * 1600000 + (size_t)id * EDIM + e];
            drow[t] = f2bf(v);
        } else if (t < 136) {
            drow[t] = f2bf(dense[b * DNUM + (t - 128)]);
        } else if (t < 192) {
            drow[1160 + (t - 136)] = 0;   // K padding
        }
        int fid = feedid[b];
        float2 f = *(const float2*)&ft[(size_t)fid * FDIM + t * 2];
        u16 u0 = f2bf(f.x), u1 = f2bf(f.y);
        drow[136 + t * 2] = u0;
        drow[136 + t * 2 + 1] = u1;
        A_q[(size_t)b * FDIM + t * 2] = u0;
        A_q[(size_t)b * FDIM + t * 2 + 1] = u1;
    }
}

// ---------- K2: generic bf16 MFMA GEMM, templated M/N tiles ----------
template<int BM, int BN, bool RELU, bool OUT_BF16>
__global__ __launch_bounds__(256, 4) void gemm_bt(
    const u16* __restrict__ A, int lda,
    const u16* __restrict__ BT, int ldb,
    const float* __restrict__ bias,
    void* __restrict__ Cv, int M, int N, int K)
{
    constexpr int MI = BM / 32;           // m-frags per wave
    constexpr int NJ = BN / 32;           // n-frags per wave
    __shared__ u16 As[BM * 64];
    __shared__ u16 Bs[BN * 64];
    int m0 = blockIdx.x * BM, n0 = blockIdx.y * BN;
    int tid = threadIdx.x, wave = tid >> 6, lane = tid & 63;
    int lrow = lane >> 3, lk = (lane & 7) * 8;
    f32x4 acc[MI][NJ];
    f32x4 zz = {0.f, 0.f, 0.f, 0.f};
    #pragma unroll
    for (int i = 0; i < MI; i++)
        #pragma unroll
        for (int j = 0; j < NJ; j++) acc[i][j] = zz;
    int wm = (wave >> 1) * (BM / 2), wn = (wave & 1) * (BN / 2);

    for (int kt = 0; kt < K; kt += 64) {
        #pragma unroll
        for (int j = 0; j < MI; ++j) {
            int c = wave * MI + j;
            int row = c * 8 + lrow;
            load16_lds(A + (size_t)(m0 + row) * lda + kt + lk, &As[c * 512]);
        }
        #pragma unroll
        for (int j = 0; j < NJ; ++j) {
            int c = wave * NJ + j;
            int row = c * 8 + lrow;
            load16_lds(BT + (size_t)(n0 + row) * ldb + kt + lk, &Bs[c * 512]);
        }
        __syncthreads();
        #pragma unroll
        for (int ks = 0; ks < 2; ++ks) {
            int kk = ks * 32 + (lane >> 4) * 8;
            short8 af[MI], bf[NJ];
            #pragma unroll
            for (int i = 0; i < MI; i++)
                af[i] = *(const short8*)&As[(wm + i * 16 + (lane & 15)) * 64 + kk];
            #pragma unroll
            for (int j = 0; j < NJ; j++)
                bf[j] = *(const short8*)&Bs[(wn + j * 16 + (lane & 15)) * 64 + kk];
            #pragma unroll
            for (int i = 0; i < MI; i++)
                #pragma unroll
                for (int j = 0; j < NJ; j++)
                    acc[i][j] = __builtin_amdgcn_mfma_f32_16x16x32_bf16(
                        af[i], bf[j], acc[i][j], 0, 0, 0);
        }
        __syncthreads();
    }
    #pragma unroll
    for (int i = 0; i < MI; i++) {
        #pragma unroll
        for (int j = 0; j < NJ; j++) {
            #pragma unroll
            for (int r = 0; r < 4; r++) {
                int row = m0 + wm + i * 16 + (lane >> 4) * 4 + r;
                int col = n0 + wn + j * 16 + (lane & 15);
                float v = acc[i][j][r];
                if (bias) v += bias[col];
                if (RELU) v = fmaxf(v, 0.f);
                size_t off = (size_t)row * N + col;
                if (OUT_BF16) ((u16*)Cv)[off] = f2bf(v);
                else ((float*)Cv)[off] = v;
            }
        }
    }
}

#define MFMA_BF16 __builtin_amdgcn_mfma_f32_16x16x32_bf16

// ---------- K3: DIN fused v23 — 256B-granularity A gather ----------
// R21 structure, but A staged at KT=64 f32 (256 B contiguous per row per
// stage): 16 lanes/row (kc=lane&15) x 4 rows/gload -> each DRAM access is
// 4 sequential lines (row-buffer hits) instead of a single scattered 64B
// line. LDS conflict-freeness via source-side chunk permutation
// (src chunk = kc ^ (ldsrow&15); read at c ^ (row&15)) — same cache lines,
// so DRAM efficiency is preserved (rule #21). A region 52 rows (pad rows
// alias row 49 at read). Per-wave counted vmcnt (wave 3 stages 1 A-gload).
__global__ __launch_bounds__(256, 3) void din_fused(
    const int* __restrict__ hist_ids, const int* __restrict__ feedid,
    const float* __restrict__ ft, const u16* __restrict__ WHP_S,
    const float* __restrict__ qw, const float* __restrict__ b1,
    const float* __restrict__ w2v, u16* __restrict__ dnn_in)
{
    __shared__ float Asf[2][52 * 64]; // 26 KB: f32 A, KT=64, swizzled chunks
    __shared__ u16 BsH[128 * 32];     // 8 KB (swizzled content)
    __shared__ u16 BsP[128 * 32];     // 8 KB
    __shared__ float qlf[512];        // 2 KB: q row (f32)
    __shared__ float qbs[128];        // qw + b1
    __shared__ float w2s[128];
    __shared__ float sred[64 * 2];
    __shared__ float scf[64];
    __shared__ int hids[64];

    int b = blockIdx.x;
    int t = threadIdx.x, w = t >> 6, lane = t & 63;
    int fr = lane & 15, kg8 = (lane >> 4) * 8;
    int wm = (w >> 1) * 32, wn = (w & 1) * 64;
    int fid = feedid[b];

    // ---- prologue: hids, qw+b1, w2, q row (f32) — plain LDS stores ----
    if (t < 64) hids[t] = hist_ids[b * LL + (t < LL ? t : LL - 1)];
    if (t < 128) {
        qbs[t] = qw[b * 128 + t] + b1[t];
        w2s[t] = w2v[t];
    }
    {
        float2 qv = *(const float2*)&ft[(size_t)fid * FDIM + t * 2];
        qlf[t * 2] = qv.x;
        qlf[t * 2 + 1] = qv.y;
    }

    // ---- A staging pointers: gload g covers LDS rows w*16+4g..+3 ----
    // lane: r4 = lane>>4 (row in group), kc = lane&15 (16B chunk position);
    // source chunk = kc ^ (ldsrow&15)  (inverse swizzle, same cache lines)
    const float* aptr[4];
    #pragma unroll
    for (int g = 0; g < 4; ++g) {
        int ldsrow = w * 16 + g * 4 + (lane >> 4);
        int real = ldsrow < LL ? ldsrow : LL - 1;
        int kc = (lane & 15) ^ (ldsrow & 15);
        aptr[g] = ft + (size_t)hist_ids[b * LL + real] * FDIM + kc * 4;
    }
    const u16* b_src0 = WHP_S + (size_t)(w * 32 + (lane >> 2)) * 1024 + (lane & 3) * 8;
    const u16* b_src1 = b_src0 + 16 * 1024;

    // ---- A read offsets (f32 idx) ----
    int row0 = wm + fr;                       // < 48, never clamps
    int row1 = wm + 16 + fr; if (row1 > LL - 1) row1 = LL - 1;
    int rb0 = row0 * 64, s0 = row0 & 15;
    int rb1 = row1 * 64, s1 = row1 & 15;
    int cl2 = (lane >> 4) * 2;                // chunk base within 32-k half

    f32x4 acc[2][4];
    f32x4 zz = {0.f, 0.f, 0.f, 0.f};
    #pragma unroll
    for (int i = 0; i < 2; i++)
        #pragma unroll
        for (int j = 0; j < 4; j++) acc[i][j] = zz;

    // ---- staging (all loads register-free via global_load_lds) ----
    #define STAGE_A(k64, buf_)                                                 \
        {                                                                      \
            load16_lds(aptr[0] + (k64) * 64, &Asf[buf_][(w * 16) * 64]);       \
            if (w < 3) {                                                       \
                load16_lds(aptr[1] + (k64) * 64, &Asf[buf_][(w * 16 + 4) * 64]); \
                load16_lds(aptr[2] + (k64) * 64, &Asf[buf_][(w * 16 + 8) * 64]); \
                load16_lds(aptr[3] + (k64) * 64, &Asf[buf_][(w * 16 + 12) * 64]); \
            }                                                                  \
        }
    #define STAGE_B(k32)                                                       \
        {                                                                      \
            const int kn_ = (k32) * 32;                                        \
            load16_lds(b_src0 + kn_,       &BsH[(w * 2) * 512]);               \
            load16_lds(b_src1 + kn_,       &BsH[(w * 2 + 1) * 512]);           \
            load16_lds(b_src0 + 512 + kn_, &BsP[(w * 2) * 512]);               \
            load16_lds(b_src1 + 512 + kn_, &BsP[(w * 2 + 1) * 512]);           \
        }

    STAGE_A(0, 0);
    STAGE_B(0);
    asm volatile("s_waitcnt vmcnt(0) lgkmcnt(0)" ::: "memory");
    __builtin_amdgcn_s_barrier();

    #pragma unroll
    for (int kt = 0; kt < 16; ++kt) {
        const int buf = (kt >> 1) & 1;
        const int ko = kt * 32;
        const int c0 = (kt & 1) * 8 + cl2;
        // ---- compute(kt): pure LDS/VALU/MFMA ----
        float4 h0a = *(const float4*)&Asf[buf][rb0 + ((c0 ^ s0) << 2)];
        float4 h0b = *(const float4*)&Asf[buf][rb0 + (((c0 + 1) ^ s0) << 2)];
        float4 h1a = *(const float4*)&Asf[buf][rb1 + ((c0 ^ s1) << 2)];
        float4 h1b = *(const float4*)&Asf[buf][rb1 + (((c0 + 1) ^ s1) << 2)];
        float4 q0a = *(const float4*)&qlf[ko + kg8];
        float4 q0b = *(const float4*)&qlf[ko + kg8 + 4];
        ushort8 hv0, hv1;
        cvt8(h0a, h0b, hv0);
        cvt8(h1a, h1b, hv1);
        short8 bh[4], bp[4];
        #pragma unroll
        for (int j = 0; j < 4; ++j) {
            int n = wn + j * 16 + fr;
            int kk = kg8 ^ ((n & 3) << 3);        // swizzled read
            bh[j] = *(const short8*)&BsH[n * 32 + kk];
            bp[j] = *(const short8*)&BsP[n * 32 + kk];
        }
        short8 ah0 = __builtin_bit_cast(short8, hv0);
        short8 ah1 = __builtin_bit_cast(short8, hv1);
        #pragma unroll
        for (int j = 0; j < 4; ++j) {
            acc[0][j] = MFMA_BF16(ah0, bh[j], acc[0][j], 0, 0, 0);
            acc[1][j] = MFMA_BF16(ah1, bh[j], acc[1][j], 0, 0, 0);
        }
        // p = bf16(h_f32 * q_f32)
        float4 p0a = make_float4(h0a.x*q0a.x, h0a.y*q0a.y, h0a.z*q0a.z, h0a.w*q0a.w);
        float4 p0b = make_float4(h0b.x*q0b.x, h0b.y*q0b.y, h0b.z*q0b.z, h0b.w*q0b.w);
        float4 p1a = make_float4(h1a.x*q0a.x, h1a.y*q0a.y, h1a.z*q0a.z, h1a.w*q0a.w);
        float4 p1b = make_float4(h1b.x*q0b.x, h1b.y*q0b.y, h1b.z*q0b.z, h1b.w*q0b.w);
        ushort8 pv0, pv1;
        cvt8(p0a, p0b, pv0);
        cvt8(p1a, p1b, pv1);
        short8 ap0 = __builtin_bit_cast(short8, pv0);
        short8 ap1 = __builtin_bit_cast(short8, pv1);
        #pragma unroll
        for (int j = 0; j < 4; ++j) {
            acc[0][j] = MFMA_BF16(ap0, bp[j], acc[0][j], 0, 0, 0);
            acc[1][j] = MFMA_BF16(ap1, bp[j], acc[1][j], 0, 0, 0);
        }
        // ---- my LDS reads done -> buffers free for overwrite ----
        asm volatile("s_waitcnt lgkmcnt(0)" ::: "memory");
        __builtin_amdgcn_s_barrier();
        // ---- issue next stages; counted drain ----
        if (kt < 15) {
            STAGE_B(kt + 1);
            if ((kt & 1) == 0 && kt < 14) {
                STAGE_A((kt >> 1) + 1, buf ^ 1);   // newest: stays in flight
                if (w < 3) { asm volatile("s_waitcnt vmcnt(4)" ::: "memory"); }
                else       { asm volatile("s_waitcnt vmcnt(1)" ::: "memory"); }
            } else {
                asm volatile("s_waitcnt vmcnt(0)" ::: "memory");
            }
            __builtin_amdgcn_s_barrier();
        }
    }
    #undef STAGE_A
    #undef STAGE_B

    // ---- epilogue 1: per-row score partials ----
    #pragma unroll
    for (int i = 0; i < 2; ++i) {
        #pragma unroll
        for (int r = 0; r < 4; ++r) {
            int rl = wm + i * 16 + (lane >> 4) * 4 + r;
            float s = 0.f;
            #pragma unroll
            for (int j = 0; j < 4; ++j) {
                int col = wn + j * 16 + fr;
                float v = acc[i][j][r] + qbs[col];
                s += fmaxf(v, 0.f) * w2s[col];
            }
            s += __shfl_xor(s, 1, 64);
            s += __shfl_xor(s, 2, 64);
            s += __shfl_xor(s, 4, 64);
            s += __shfl_xor(s, 8, 64);
            if (fr == 0) sred[rl * 2 + (w & 1)] = s;
        }
    }
    __syncthreads();
    if (t < 64) scf[t] = sred[t * 2] + sred[t * 2 + 1];
    __syncthreads();
    // ---- epilogue 2: softmax over 50 ----
    if (w == 0) {
        float x = (lane < LL) ? scf[lane] : -1e30f;
        float mx = wave_max(x);
        float e = (lane < LL) ? __expf(x - mx) : 0.f;
        float s = wave_sum(e);
        scf[lane] = (lane < LL) ? e / s : 0.f;
    }
    __syncthreads();
    // ---- epilogue 3: user_interest (h rows L1/L2-hot from the gather) ----
    int d = t * 2;
    float a0 = 0.f, a1 = 0.f;
    #pragma unroll 5
    for (int l = 0; l < LL; ++l) {
        float2 hv = *(const float2*)&ft[(size_t)hids[l] * FDIM + d];
        float al = scf[l];
        a0 += al * hv.x;
        a1 += al * hv.y;
    }
    dnn_in[(size_t)b * KDNN + 648 + d] = f2bf(a0);
    dnn_in[(size_t)b * KDNN + 648 + d + 1] = f2bf(a1);
}

// ---------- K5: MMOE + task heads ----------
__global__ __launch_bounds__(256) void mmoe_head(
    const float* __restrict__ dnn_out, const float* __restrict__ expert_w,
    const float* __restrict__ gate_w, const float* __restrict__ out_w,
    const float* __restrict__ out_b, float* __restrict__ out)
{
    int wave = threadIdx.x >> 6, lane = threadIdx.x & 63;
    int b = blockIdx.x * 4 + wave;
    __shared__ float ds[4][128];
    __shared__ float eo[4][64];
    __shared__ float gt[4][32];
    ds[wave][lane] = dnn_out[b * 128 + lane];
    ds[wave][lane + 64] = dnn_out[b * 128 + 64 + lane];
    __syncthreads();
    int e = lane >> 3, o = lane & 7;
    float acc = 0.f;
    for (int k = 0; k < 128; ++k)
        acc += ds[wave][k] * expert_w[(e * 128 + k) * 8 + o];
    eo[wave][lane] = acc;
    if (lane < 32) {
        int tt = lane >> 3, ee = lane & 7;
        float g = 0.f;
        for (int k = 0; k < 128; ++k)
            g += ds[wave][k] * gate_w[(tt * 128 + k) * 8 + ee];
        float m = g;
        #pragma unroll
        for (int off = 4; off; off >>= 1) m = fmaxf(m, __shfl_xor(m, off, 8));
        float ex = __expf(g - m);
        float s = ex;
        #pragma unroll
        for (int off = 4; off; off >>= 1) s += __shfl_xor(s, off, 8);
        gt[wave][lane] = ex / s;
    }
    __syncthreads();
    if (lane < 32) {
        int tt = lane >> 3, o2 = lane & 7;
        float to = 0.f;
        #pragma unroll
        for (int ee = 0; ee < 8; ++ee)
            to += gt[wave][tt * 8 + ee] * eo[wave][ee * 8 + o2];
        float pl = to * out_w[tt * 8 + o2];
        #pragma unroll
        for (int off = 4; off; off >>= 1) pl += __shfl_xor(pl, off, 8);
        if (o2 == 0) {
            float logit = pl + out_b[tt];
            out[b * 4 + tt] = 1.f / (1.f + __expf(-logit));
        }
    }
}

// ---------- host ----------
extern "C" void kernel_launch(void* const* d_in, const int* in_sizes, int n_in,
                              void* d_out, int out_size, void* d_ws, size_t ws_size,
                              hipStream_t stream)
{
    const int*   sparse_ids = (const int*)d_in[0];
    const float* dense      = (const float*)d_in[1];
    const int*   feedid     = (const int*)d_in[2];
    const int*   hist_ids   = (const int*)d_in[3];
    const float* emb_tables = (const float*)d_in[4];
    const float* feed_table = (const float*)d_in[5];
    const float* attn_w1    = (const float*)d_in[6];
    const float* attn_b1    = (const float*)d_in[7];
    const float* attn_w2    = (const float*)d_in[8];
    const float* attn_b2    = (const float*)d_in[9];
    const float* dnn_w1     = (const float*)d_in[10];
    const float* dnn_b1     = (const float*)d_in[11];
    const float* dnn_w2     = (const float*)d_in[12];
    const float* dnn_b2     = (const float*)d_in[13];
    const float* expert_w   = (const float*)d_in[14];
    const float* gate_w     = (const float*)d_in[15];
    const float* out_w      = (const float*)d_in[16];
    const float* out_b      = (const float*)d_in[17];
    float* out = (float*)d_out;
    (void)attn_b2;   // dropped by softmax invariance

    char* ws = (char*)d_ws;
    size_t off = 0;
    auto alloc = [&](size_t bytes) {
        char* p = ws + off;
        off += (bytes + 255) & ~(size_t)255;
        return p;
    };
    u16* WHP_S = (u16*)alloc(131072 * 2);
    u16* WQ_T  = (u16*)alloc(65536 * 2);
    u16* W1D_T = (u16*)alloc((size_t)HID1 * KDNN * 2);
    u16* W2D_T = (u16*)alloc((size_t)HID2 * HID1 * 2);
    u16* AQ    = (u16*)alloc((size_t)BB * FDIM * 2);
    float* QW  = (float*)alloc((size_t)BB * 128 * 4);
    u16* DNNIN = (u16*)alloc((size_t)BB * KDNN * 2);
    u16* Z     = (u16*)alloc((size_t)BB * HID1 * 2);
    float* DOUT= (float*)alloc((size_t)BB * HID2 * 4);

    prep_small<<<PREP_BLKS + BB, 256, 0, stream>>>(
        feed_table, attn_w1, dnn_w1, dnn_w2,
        WHP_S, WQ_T, W1D_T, W2D_T,
        sparse_ids, dense, feedid, emb_tables, DNNIN, AQ);
    gemm_bt<32, 64, false, false><<<dim3(BB / 32, 2), 256, 0, stream>>>(
        AQ, 512, WQ_T, 512, nullptr, QW, BB, 128, 512);
    din_fused<<<BB, 256, 0, stream>>>(
        hist_ids, feedid, feed_table, WHP_S, QW, attn_b1, attn_w2, DNNIN);
    gemm_bt<32, 64, true, true><<<dim3(BB / 32, HID1 / 64), 256, 0, stream>>>(
        DNNIN, KDNN, W1D_T, KDNN, dnn_b1, Z, BB, HID1, KDNN);
    gemm_bt<32, 64, true, false><<<dim3(BB / 32, HID2 / 64), 256, 0, stream>>>(
        Z, HID1, W2D_T, HID1, dnn_b2, DOUT, BB, HID2, HID1);
    mmoe_head<<<BB / 4, 256, 0, stream>>>(DOUT, expert_w, gate_w, out_w,
                                          out_b, out);
}